// Round 6
// baseline (84.762 us; speedup 1.0000x reference)
//
#include <hip/hip_runtime.h>

// out[b,o,h,w] = sum_{c,k} (coef[k]/12.5) * rint( sum_j (12.5*w[k,c,o,j])*x_j + 12.5*b[k,c,o] )
// R6: R5's packed-fp32 2-row wave shape + 2-deep channel prefetch (register ping-pong)
// + direct pair-slot loads (no t-pack movs). 8192 waves = 8/SIMD; VGPR budget <=64.

typedef float v2f __attribute__((ext_vector_type(2)));

#define NB     8
#define NC     32
#define NO     32
#define NH     64
#define NW     64
#define NBATCH 8
#define FST    10                  // 9 taps + bias
#define PLANE  (NH * NW)
#define WCSTEP (NO * NB * FST)     // dwords per c step in wq

// wq layout: [c:32][o:32][k:8][10]; value = 12.5*w, [9] = 12.5*bias
__global__ void prep_wq(const float* __restrict__ w, const float* __restrict__ bias,
                        float* __restrict__ wq) {
    int idx = blockIdx.x * 256 + threadIdx.x;      // (c*32+o)*8+k
    if (idx >= NC * NO * NB) return;
    int k  = idx & 7;
    int ch = idx >> 3;                             // c*32+o
    const float* ws = w + ((size_t)k * (NC * NO) + ch) * 9;
    float* dst = wq + (size_t)idx * FST;
#pragma unroll
    for (int j = 0; j < 9; ++j) dst[j] = 12.5f * ws[j];
    dst[9] = 12.5f * bias[k * (NC * NO) + ch];
}

struct Taps { v2f t[9]; };   // t[3r+cc] = { x[h0-1+r][w+cc-1], x[h0+r][w+cc-1] }

__device__ __forceinline__ Taps load_taps(
        const float* __restrict__ X, int o,
        int rT, int rB, int iL, int iR,
        bool okL, bool okR, bool top, bool bot,
        bool mTL, bool mTR, bool mBL, bool mBR) {
    // 12 unique loads (rows h0-1(clamped), h0, h0+1, h0+2(clamped) x cols L,C,R)
    float xm1L = X[o + rT + iL], xm1C = X[o + rT], xm1R = X[o + rT + iR];
    float x0L  = X[o + iL],      x0C  = X[o],      x0R  = X[o + iR];
    float x1L  = X[o + NW + iL], x1C  = X[o + NW], x1R  = X[o + NW + iR];
    float x2L  = X[o + rB + iL], x2C  = X[o + rB], x2R  = X[o + rB + iR];
    Taps r;
    r.t[0].x = mTL ? xm1L : 0.f;  r.t[0].y = okL ? x0L : 0.f;
    r.t[1].x = top ? xm1C : 0.f;  r.t[1].y = x0C;
    r.t[2].x = mTR ? xm1R : 0.f;  r.t[2].y = okR ? x0R : 0.f;
    r.t[3].x = r.t[0].y;          r.t[3].y = okL ? x1L : 0.f;
    r.t[4].x = x0C;               r.t[4].y = x1C;
    r.t[5].x = r.t[2].y;          r.t[5].y = okR ? x1R : 0.f;
    r.t[6].x = r.t[3].y;          r.t[6].y = mBL ? x2L : 0.f;
    r.t[7].x = x1C;               r.t[7].y = bot ? x2C : 0.f;
    r.t[8].x = r.t[5].y;          r.t[8].y = mBR ? x2R : 0.f;
    return r;
}

__device__ __forceinline__ v2f compute8(const float* __restrict__ wq, int woff,
                                        const Taps& T, v2f acc, const float* ckq) {
    const float* wp = wq + __builtin_amdgcn_readfirstlane(woff);
#pragma unroll
    for (int k = 0; k < NB; ++k) {
        const float* f = wp + k * FST;             // compile-time imm offsets off scalar base
        v2f s; s.x = f[9]; s.y = f[9];             // pre-scaled bias (both rows)
#pragma unroll
        for (int j = 0; j < 9; ++j) {
            v2f wv; wv.x = f[j]; wv.y = f[j];      // uniform splat
            s = __builtin_elementwise_fma(wv, T.t[j], s);
        }
        v2f rr; rr.x = rintf(s.x); rr.y = rintf(s.y);
        v2f cv; cv.x = ckq[k]; cv.y = ckq[k];
        acc = __builtin_elementwise_fma(cv, rr, acc);
    }
    return acc;
}

// Wave = (b, o, row-pair h0,h0+1). lane = w. Grid (32,8,8) -> 8192 waves = 32/CU.
__global__ __launch_bounds__(256, 8) void demolition_conv(
        const float* __restrict__ x, const float* __restrict__ wq,
        float* __restrict__ out) {
    const int w    = threadIdx.x & 63;
    const int wave = threadIdx.x >> 6;
    const int o    = blockIdx.x;                   // 0..31
    const int h0   = blockIdx.y * 8 + wave * 2;    // 0..62 even
    const int b    = blockIdx.z;

    const float ckq[8] = {
        -128.f / 127.f / 12.5f,  1.f / 127.f / 12.5f,  2.f / 127.f / 12.5f,
           4.f / 127.f / 12.5f,  8.f / 127.f / 12.5f, 16.f / 127.f / 12.5f,
          32.f / 127.f / 12.5f, 64.f / 127.f / 12.5f };

    v2f acc = {0.f, 0.f};

    const bool okL = (w > 0), okR = (w < NW - 1);
    const bool top = (h0 > 0), bot = (h0 < NH - 2);
    const bool mTL = top && okL, mTR = top && okR;
    const bool mBL = bot && okL, mBR = bot && okR;
    const int  iL  = okL ? -1 : 0;
    const int  iR  = okR ?  1 : 0;
    const int  rT  = top ? -NW : 0;        // row h0-1, clamped (value masked)
    const int  rB  = bot ? 2 * NW : NW;    // row h0+2, clamped (value masked)

    int offc = ((b * NC) * NH + h0) * NW + w;      // 32-bit element offset (saddr form)
    int woff = o * (NB * FST);

    // 2-deep channel ping-pong: loads for c+1 issued before compute of c
    Taps A = load_taps(x, offc, rT, rB, iL, iR, okL, okR, top, bot, mTL, mTR, mBL, mBR);
    offc += PLANE;
    Taps B;
#pragma unroll 1
    for (int c = 0; c < NC - 2; c += 2) {
        B = load_taps(x, offc, rT, rB, iL, iR, okL, okR, top, bot, mTL, mTR, mBL, mBR);
        offc += PLANE;
        acc = compute8(wq, woff, A, acc, ckq);  woff += WCSTEP;
        A = load_taps(x, offc, rT, rB, iL, iR, okL, okR, top, bot, mTL, mTR, mBL, mBR);
        offc += PLANE;
        acc = compute8(wq, woff, B, acc, ckq);  woff += WCSTEP;
    }
    B = load_taps(x, offc, rT, rB, iL, iR, okL, okR, top, bot, mTL, mTR, mBL, mBR);
    acc = compute8(wq, woff, A, acc, ckq);  woff += WCSTEP;
    acc = compute8(wq, woff, B, acc, ckq);

    float* o0 = out + (((size_t)b * NO + o) * NH + h0) * NW + w;
    o0[0]  = acc.x;
    o0[NW] = acc.y;
}

extern "C" void kernel_launch(void* const* d_in, const int* in_sizes, int n_in,
                              void* d_out, int out_size, void* d_ws, size_t ws_size,
                              hipStream_t stream) {
    const float* x    = (const float*)d_in[0];   // [8,32,64,64]
    const float* wt   = (const float*)d_in[1];   // [8,1024,1,3,3]
    const float* bias = (const float*)d_in[2];   // [8,1024]
    float* out = (float*)d_out;                  // [8,32,64,64]
    float* wq  = (float*)d_ws;                   // 8192*10 floats = 320 KiB

    prep_wq<<<(NC * NO * NB + 255) / 256, 256, 0, stream>>>(wt, bias, wq);

    dim3 grid(NO, 8, NBATCH);                    // (o, h-block, b)
    demolition_conv<<<grid, 256, 0, stream>>>(x, wq, out);
}